// Round 9
// baseline (443.291 us; speedup 1.0000x reference)
//
#include <hip/hip_runtime.h>

#define TT    512
#define HH    64
#define NB    4
#define NBLK  256
#define HP    72    // h^T pitch in f16

#define LOG2E 1.44269504f

typedef _Float16 f16x8 __attribute__((ext_vector_type(8)));
typedef _Float16 f16x4 __attribute__((ext_vector_type(4)));
typedef float    f32x4 __attribute__((ext_vector_type(4)));

#if __has_builtin(__builtin_amdgcn_exp2f)
#define EXP2(x) __builtin_amdgcn_exp2f(x)
#else
#define EXP2(x) exp2f(x)
#endif

// r18: exp2/sign folding into weight rows. Gate rows are pre-scaled at
// fragment load: i,f,o rows x(-log2e)  -> sigmoid = rcp(1+exp2(gate));
//                g row     x(+2*log2e) -> tanh    = 1-2*rcp(1+exp2(gate)).
// This deletes the per-sigmoid negate and all the x*log2e pre-multiplies
// that __expf emits (~11-13 VALU inst per gate-set). r17 established the
// kernel is ISSUE-bound on the pointwise VALU stream (divide fix: -19%,
// ~1:1 cycles-removed to cycles-gained), so keep cutting issue.
// Scaled weights are rounded to f16 AFTER scaling (same relative error);
// fp32 accumulation is exact in scale -> absmax stays in the 4e-3 class.
// Also: C-group 4-chain split into two 2-chains + fp32 add (validated
// r10/r14, absmax fine) — removes ~70cy of MFMA chain for free.
// sigmoidf-style rcp (r17): v_rcp_f32, ~1ulp, saturates gracefully.
//
// Body otherwise = r17 (= r9 + fast pointwise), the proven 374us kernel.
// 256 blocks x 512 threads. Group A = waves 0-3 (layer 1), group C = waves
// 4-7 (layer 2, fused K=128 over [h1; h2]). Wave w owns M-tiles
// {w,w+4,w+8,w+12}; cell transpose -> 1 cell/lane pointwise on 64 lanes.
// LESSONS: r8 cross-block handoff 4x. r10 pointwise on 16 lanes 2x (wave
// cost is per-inst, not per-lane). r12 512t blocks never co-reside at
// ~160 regs (per-CU pool ~2048). r13 fat 2-wave 2.2x. r14 chain cuts
// neutral (pre-r17). r15 fat waves + spill. r16 spin-barriers 10% worse.
// r17 pointwise divide fix -19% — ISSUE-BOUND regime confirmed.
__device__ __forceinline__ float sig2_(float xs) {   // xs = -x*log2e (pre-folded)
    return __builtin_amdgcn_rcpf(1.0f + EXP2(xs));
}
__device__ __forceinline__ float tanh2_(float xs) {  // xs = 2x*log2e (pre-folded)
    return 1.0f - 2.0f * __builtin_amdgcn_rcpf(1.0f + EXP2(xs));
}

__global__ __launch_bounds__(512) void lstm_mfma(
    const float* __restrict__ x,
    const float* __restrict__ w_ih0, const float* __restrict__ w_hh0,
    const float* __restrict__ b_ih0, const float* __restrict__ b_hh0,
    const float* __restrict__ w_ih1, const float* __restrict__ w_hh1,
    const float* __restrict__ b_ih1, const float* __restrict__ b_hh1,
    const float* __restrict__ w_out, const float* __restrict__ b_out,
    float* __restrict__ out)
{
    __shared__ __align__(16) _Float16 h1T[2][16 * HP];  // h1^T [batch][unit] f16
    __shared__ __align__(16) _Float16 h2T[2][16 * HP];  // h2^T
    __shared__ float xs[TT * 12];                       // x [t][d][4] fp32
    __shared__ __align__(16) f32x4 cellA[4][64];        // A gate transpose
    __shared__ __align__(16) f32x4 cellC[4][64];        // C gate transpose
    __shared__ __align__(16) float h2f[16 * 68];        // final h2 fp32
    __shared__ float lg[NB][4];

    const int tid   = threadIdx.x;
    const int group = tid >> 8;          // 0 = A (layer 1), 1 = C (layer 2)
    const int w     = (tid >> 6) & 3;    // wave-in-group
    const int lane  = tid & 63;
    const int quad  = lane >> 4;
    const int n     = lane & 15;         // MFMA column = batch slot
    const int b0    = blockIdx.x * NB;

    const int cu    = lane >> 2;                      // unit after transpose
    const int cb    = lane & 3;                       // batch after transpose
    const int rdslot = lane ^ ((lane >> 4) << 2);     // XOR-swizzled cell slot

    // ---- persistent weight fragments (gate-scaled: i,f,o x-log2e, g x2log2e) ----
    f16x8 whh[4][2], wih[4][2], axf[4];
    f32x4 biasf[4];
    #pragma unroll
    for (int g_ = 0; g_ < 4; ++g_) {
        const float sc = (g_ == 2) ? (2.0f * LOG2E) : (-LOG2E);
        const int arow = 16 * w + 64 * g_ + n;        // A-frag row m = lane&15
        const float* ph = (group == 0) ? (w_hh0 + arow * HH) : (w_hh1 + arow * HH);
        const float* pi = w_ih1 + arow * HH;
        #pragma unroll
        for (int k0 = 0; k0 < 2; ++k0) {
            #pragma unroll
            for (int j = 0; j < 8; ++j) {
                whh[g_][k0][j] = (_Float16)(sc * ph[quad * 8 + 32 * k0 + j]);
                wih[g_][k0][j] = (group == 1) ? (_Float16)(sc * pi[quad * 8 + 32 * k0 + j])
                                              : (_Float16)0.f;
            }
        }
        #pragma unroll
        for (int r = 0; r < 4; ++r) {                 // C/D row = quad*4 + r
            const int crow = 16 * w + 64 * g_ + quad * 4 + r;
            biasf[g_][r] = sc * ((group == 0) ? (b_ih0[crow] + b_hh0[crow])
                                              : (b_ih1[crow] + b_hh1[crow]));
        }
        f16x8 ax;
        #pragma unroll
        for (int j = 0; j < 8; ++j) ax[j] = (_Float16)0.f;
        if (group == 0 && quad == 0) {                // K=3 x-transform (scaled)
            ax[0] = (_Float16)(sc * w_ih0[arow * 3 + 0]);
            ax[1] = (_Float16)(sc * w_ih0[arow * 3 + 1]);
            ax[2] = (_Float16)(sc * w_ih0[arow * 3 + 2]);
        }
        axf[g_] = ax;
    }

    // ---- LDS init ----
    for (int i = tid; i < 1152; i += 512) {
        ((int*)h1T)[i] = 0;
        ((int*)h2T)[i] = 0;
    }
    for (int i = tid; i < TT * 12; i += 512) {
        const int t = i / 12, rem = i - t * 12;
        const int d = rem >> 2, b = rem & 3;
        xs[i] = x[(size_t)(b0 + b) * (TT * 3) + t * 3 + d];
    }
    __syncthreads();

    float creg = 0.f;    // A: c1 of (unit 16w+cu, batch cb); C: c2 of same

    for (int t = 0; t <= TT; ++t) {
        if (group == 0) {
            if (t < TT) {
                f16x8 bx;
                #pragma unroll
                for (int j = 0; j < 8; ++j) bx[j] = (_Float16)0.f;
                if (quad == 0) {
                    const float* xp = xs + t * 12 + (lane & 3);
                    bx[0] = (_Float16)xp[0];
                    bx[1] = (_Float16)xp[4];
                    bx[2] = (_Float16)xp[8];
                }
                const _Float16* hsrc = h1T[(t + 1) & 1];
                const f16x8 bh0 = *(const f16x8*)(hsrc + n * HP + quad * 8);
                const f16x8 bh1 = *(const f16x8*)(hsrc + n * HP + quad * 8 + 32);
                f32x4 acc[4];
                #pragma unroll
                for (int g_ = 0; g_ < 4; ++g_) {
                    f32x4 a = __builtin_amdgcn_mfma_f32_16x16x32_f16(axf[g_], bx, biasf[g_], 0, 0, 0);
                    a = __builtin_amdgcn_mfma_f32_16x16x32_f16(whh[g_][0], bh0, a, 0, 0, 0);
                    a = __builtin_amdgcn_mfma_f32_16x16x32_f16(whh[g_][1], bh1, a, 0, 0, 0);
                    acc[g_] = a;
                }
                if (n < 4) {
                    #pragma unroll
                    for (int r = 0; r < 4; ++r) {
                        const int slot = (16 * quad + 4 * r + n) ^ (quad << 2);
                        f32x4 v = {acc[0][r], acc[1][r], acc[2][r], acc[3][r]};
                        cellA[w][slot] = v;
                    }
                }
                const f32x4 gate = cellA[w][rdslot];
                const float is = sig2_(gate[0]);
                const float fs = sig2_(gate[1]);
                const float gt = tanh2_(gate[2]);
                const float os = sig2_(gate[3]);
                creg = fs * creg + is * gt;
                h1T[t & 1][cb * HP + 16 * w + cu] =
                    (_Float16)(os * tanh2_(creg * (2.0f * LOG2E)));
            }
        } else {
            if (t >= 1) {
                // fused K=128 matvec over [h1(t-1); h2(t-2)], split 2+2 chains
                const _Float16* h1src = h1T[(t + 1) & 1];
                const _Float16* h2src = h2T[(t + 1) & 1];
                const f16x8 b10 = *(const f16x8*)(h1src + n * HP + quad * 8);
                const f16x8 b11 = *(const f16x8*)(h1src + n * HP + quad * 8 + 32);
                const f16x8 b20 = *(const f16x8*)(h2src + n * HP + quad * 8);
                const f16x8 b21 = *(const f16x8*)(h2src + n * HP + quad * 8 + 32);
                const f32x4 zero4 = {0.f, 0.f, 0.f, 0.f};
                f32x4 acc[4];
                #pragma unroll
                for (int g_ = 0; g_ < 4; ++g_) {
                    f32x4 p = __builtin_amdgcn_mfma_f32_16x16x32_f16(wih[g_][0], b10, biasf[g_], 0, 0, 0);
                    p = __builtin_amdgcn_mfma_f32_16x16x32_f16(wih[g_][1], b11, p, 0, 0, 0);
                    f32x4 q4 = __builtin_amdgcn_mfma_f32_16x16x32_f16(whh[g_][0], b20, zero4, 0, 0, 0);
                    q4 = __builtin_amdgcn_mfma_f32_16x16x32_f16(whh[g_][1], b21, q4, 0, 0, 0);
                    acc[g_] = p + q4;
                }
                if (n < 4) {
                    #pragma unroll
                    for (int r = 0; r < 4; ++r) {
                        const int slot = (16 * quad + 4 * r + n) ^ (quad << 2);
                        f32x4 v = {acc[0][r], acc[1][r], acc[2][r], acc[3][r]};
                        cellC[w][slot] = v;
                    }
                }
                const f32x4 gate = cellC[w][rdslot];
                const float is = sig2_(gate[0]);
                const float fs = sig2_(gate[1]);
                const float gt = tanh2_(gate[2]);
                const float os = sig2_(gate[3]);
                creg = fs * creg + is * gt;
                const float h = os * tanh2_(creg * (2.0f * LOG2E));
                h2T[t & 1][cb * HP + 16 * w + cu] = (_Float16)h;   // h2(t-1)
                if (t == TT) h2f[cb * 68 + 16 * w + cu] = h;       // h2(TT-1) fp32
            }
        }
        __syncthreads();
    }

    // ---- epilogue: logits + softmax on fp32 h2 ----
    if (tid < 16) {
        const int b = tid & 3, o = tid >> 2;
        float acc = b_out[o];
        #pragma unroll
        for (int j = 0; j < HH; ++j)
            acc = fmaf(w_out[o * HH + j], h2f[b * 68 + j], acc);
        lg[b][o] = acc;
    }
    __syncthreads();
    if (tid < NB) {
        const int b = tid;
        const float l0 = lg[b][0], l1 = lg[b][1], l2 = lg[b][2], l3 = lg[b][3];
        const float m  = fmaxf(fmaxf(l0, l1), fmaxf(l2, l3));
        const float e0 = __expf(l0 - m), e1 = __expf(l1 - m);
        const float e2 = __expf(l2 - m), e3 = __expf(l3 - m);
        const float sum = 1.0f / (e0 + e1 + e2 + e3);
        out[(b0 + b) * 4 + 0] = e0 * sum;
        out[(b0 + b) * 4 + 1] = e1 * sum;
        out[(b0 + b) * 4 + 2] = e2 * sum;
        out[(b0 + b) * 4 + 3] = e3 * sum;
    }
}

extern "C" void kernel_launch(void* const* d_in, const int* in_sizes, int n_in,
                              void* d_out, int out_size, void* d_ws, size_t ws_size,
                              hipStream_t stream) {
    const float* x     = (const float*)d_in[0];
    const float* w_ih0 = (const float*)d_in[1];
    const float* w_hh0 = (const float*)d_in[2];
    const float* b_ih0 = (const float*)d_in[3];
    const float* b_hh0 = (const float*)d_in[4];
    const float* w_ih1 = (const float*)d_in[5];
    const float* w_hh1 = (const float*)d_in[6];
    const float* b_ih1 = (const float*)d_in[7];
    const float* b_hh1 = (const float*)d_in[8];
    const float* w_out = (const float*)d_in[9];
    const float* b_out = (const float*)d_in[10];
    float* out = (float*)d_out;

    hipLaunchKernelGGL(lstm_mfma, dim3(NBLK), dim3(512), 0, stream,
                       x, w_ih0, w_hh0, b_ih0, b_hh0,
                       w_ih1, w_hh1, b_ih1, b_hh1,
                       w_out, b_out, out);
}

// Round 10
// 407.018 us; speedup vs baseline: 1.0891x; 1.0891x over previous
//
#include <hip/hip_runtime.h>

#define TT    512
#define HH    64
#define NB    4
#define NBLK  256
#define HP    72    // h^T pitch in f16

#define LOG2E 1.44269504f

typedef _Float16 f16x8 __attribute__((ext_vector_type(8)));
typedef _Float16 f16x4 __attribute__((ext_vector_type(4)));
typedef float    f32x4 __attribute__((ext_vector_type(4)));

#if __has_builtin(__builtin_amdgcn_exp2f)
#define EXP2(x) __builtin_amdgcn_exp2f(x)
#else
#define EXP2(x) exp2f(x)
#endif

// r19 = r17 (374us proven) + r18's exp2/sign weight folding ONLY.
// r18's C-group 2+2 chain split is REVERTED: it kept 8 accumulator chains
// live and put AGPR->VGPR reads + vector adds (p+q4) on the critical path
// before the cell transpose — r18 post-mortem: VALU-time fell 142->135us
// (folding worked) but duration rose 374->414us (split added stall).
// Folding: gate rows pre-scaled at fragment load: i,f,o rows x(-log2e) ->
// sigmoid = rcp(1+exp2(g)); g rows x(+2*log2e) -> tanh = 1-2*rcp(1+exp2(g)).
// Scaled weights rounded to f16 AFTER scaling; fp32 accum exact in scale.
// 256 blocks x 512 threads. Group A = waves 0-3 (layer 1), group C = waves
// 4-7 (layer 2, fused K=128 over [h1; h2], 4-deep chained MFMA). Wave w
// owns M-tiles {w,w+4,w+8,w+12}; cell transpose -> 1 cell/lane pointwise.
// LESSONS: r8 cross-block 4x. r10 pointwise on 16 lanes 2x. r12 512t
// blocks never co-reside. r13 fat 2-wave 2.2x. r14 chain cuts neutral.
// r15 fat waves spill. r16 spin-barriers worse. r17 divide->rcp -19%
// (ISSUE-bound). r18 C-split regression: keep ONE accumulator chain per
// tile; never bundle two changes.
__device__ __forceinline__ float sig2_(float xs) {   // xs = -x*log2e (pre-folded)
    return __builtin_amdgcn_rcpf(1.0f + EXP2(xs));
}
__device__ __forceinline__ float tanh2_(float xs) {  // xs = 2x*log2e (pre-folded)
    return 1.0f - 2.0f * __builtin_amdgcn_rcpf(1.0f + EXP2(xs));
}

__global__ __launch_bounds__(512) void lstm_mfma(
    const float* __restrict__ x,
    const float* __restrict__ w_ih0, const float* __restrict__ w_hh0,
    const float* __restrict__ b_ih0, const float* __restrict__ b_hh0,
    const float* __restrict__ w_ih1, const float* __restrict__ w_hh1,
    const float* __restrict__ b_ih1, const float* __restrict__ b_hh1,
    const float* __restrict__ w_out, const float* __restrict__ b_out,
    float* __restrict__ out)
{
    __shared__ __align__(16) _Float16 h1T[2][16 * HP];  // h1^T [batch][unit] f16
    __shared__ __align__(16) _Float16 h2T[2][16 * HP];  // h2^T
    __shared__ float xs[TT * 12];                       // x [t][d][4] fp32
    __shared__ __align__(16) f32x4 cellA[4][64];        // A gate transpose
    __shared__ __align__(16) f32x4 cellC[4][64];        // C gate transpose
    __shared__ __align__(16) float h2f[16 * 68];        // final h2 fp32
    __shared__ float lg[NB][4];

    const int tid   = threadIdx.x;
    const int group = tid >> 8;          // 0 = A (layer 1), 1 = C (layer 2)
    const int w     = (tid >> 6) & 3;    // wave-in-group
    const int lane  = tid & 63;
    const int quad  = lane >> 4;
    const int n     = lane & 15;         // MFMA column = batch slot
    const int b0    = blockIdx.x * NB;

    const int cu    = lane >> 2;                      // unit after transpose
    const int cb    = lane & 3;                       // batch after transpose
    const int rdslot = lane ^ ((lane >> 4) << 2);     // XOR-swizzled cell slot

    // ---- persistent weight fragments (gate-scaled: i,f,o x-log2e, g x2log2e) ----
    f16x8 whh[4][2], wih[4][2], axf[4];
    f32x4 biasf[4];
    #pragma unroll
    for (int g_ = 0; g_ < 4; ++g_) {
        const float sc = (g_ == 2) ? (2.0f * LOG2E) : (-LOG2E);
        const int arow = 16 * w + 64 * g_ + n;        // A-frag row m = lane&15
        const float* ph = (group == 0) ? (w_hh0 + arow * HH) : (w_hh1 + arow * HH);
        const float* pi = w_ih1 + arow * HH;
        #pragma unroll
        for (int k0 = 0; k0 < 2; ++k0) {
            #pragma unroll
            for (int j = 0; j < 8; ++j) {
                whh[g_][k0][j] = (_Float16)(sc * ph[quad * 8 + 32 * k0 + j]);
                wih[g_][k0][j] = (group == 1) ? (_Float16)(sc * pi[quad * 8 + 32 * k0 + j])
                                              : (_Float16)0.f;
            }
        }
        #pragma unroll
        for (int r = 0; r < 4; ++r) {                 // C/D row = quad*4 + r
            const int crow = 16 * w + 64 * g_ + quad * 4 + r;
            biasf[g_][r] = sc * ((group == 0) ? (b_ih0[crow] + b_hh0[crow])
                                              : (b_ih1[crow] + b_hh1[crow]));
        }
        f16x8 ax;
        #pragma unroll
        for (int j = 0; j < 8; ++j) ax[j] = (_Float16)0.f;
        if (group == 0 && quad == 0) {                // K=3 x-transform (scaled)
            ax[0] = (_Float16)(sc * w_ih0[arow * 3 + 0]);
            ax[1] = (_Float16)(sc * w_ih0[arow * 3 + 1]);
            ax[2] = (_Float16)(sc * w_ih0[arow * 3 + 2]);
        }
        axf[g_] = ax;
    }

    // ---- LDS init ----
    for (int i = tid; i < 1152; i += 512) {
        ((int*)h1T)[i] = 0;
        ((int*)h2T)[i] = 0;
    }
    for (int i = tid; i < TT * 12; i += 512) {
        const int t = i / 12, rem = i - t * 12;
        const int d = rem >> 2, b = rem & 3;
        xs[i] = x[(size_t)(b0 + b) * (TT * 3) + t * 3 + d];
    }
    __syncthreads();

    float creg = 0.f;    // A: c1 of (unit 16w+cu, batch cb); C: c2 of same

    for (int t = 0; t <= TT; ++t) {
        if (group == 0) {
            if (t < TT) {
                f16x8 bx;
                #pragma unroll
                for (int j = 0; j < 8; ++j) bx[j] = (_Float16)0.f;
                if (quad == 0) {
                    const float* xp = xs + t * 12 + (lane & 3);
                    bx[0] = (_Float16)xp[0];
                    bx[1] = (_Float16)xp[4];
                    bx[2] = (_Float16)xp[8];
                }
                const _Float16* hsrc = h1T[(t + 1) & 1];
                const f16x8 bh0 = *(const f16x8*)(hsrc + n * HP + quad * 8);
                const f16x8 bh1 = *(const f16x8*)(hsrc + n * HP + quad * 8 + 32);
                f32x4 acc[4];
                #pragma unroll
                for (int g_ = 0; g_ < 4; ++g_) {
                    f32x4 a = __builtin_amdgcn_mfma_f32_16x16x32_f16(axf[g_], bx, biasf[g_], 0, 0, 0);
                    a = __builtin_amdgcn_mfma_f32_16x16x32_f16(whh[g_][0], bh0, a, 0, 0, 0);
                    a = __builtin_amdgcn_mfma_f32_16x16x32_f16(whh[g_][1], bh1, a, 0, 0, 0);
                    acc[g_] = a;
                }
                if (n < 4) {
                    #pragma unroll
                    for (int r = 0; r < 4; ++r) {
                        const int slot = (16 * quad + 4 * r + n) ^ (quad << 2);
                        f32x4 v = {acc[0][r], acc[1][r], acc[2][r], acc[3][r]};
                        cellA[w][slot] = v;
                    }
                }
                const f32x4 gate = cellA[w][rdslot];
                const float is = sig2_(gate[0]);
                const float fs = sig2_(gate[1]);
                const float gt = tanh2_(gate[2]);
                const float os = sig2_(gate[3]);
                creg = fs * creg + is * gt;
                h1T[t & 1][cb * HP + 16 * w + cu] =
                    (_Float16)(os * tanh2_(creg * (2.0f * LOG2E)));
            }
        } else {
            if (t >= 1) {
                // fused K=128 matvec over [h1(t-1); h2(t-2)], 4-deep chain (r17)
                const _Float16* h1src = h1T[(t + 1) & 1];
                const _Float16* h2src = h2T[(t + 1) & 1];
                const f16x8 b10 = *(const f16x8*)(h1src + n * HP + quad * 8);
                const f16x8 b11 = *(const f16x8*)(h1src + n * HP + quad * 8 + 32);
                const f16x8 b20 = *(const f16x8*)(h2src + n * HP + quad * 8);
                const f16x8 b21 = *(const f16x8*)(h2src + n * HP + quad * 8 + 32);
                f32x4 acc[4];
                #pragma unroll
                for (int g_ = 0; g_ < 4; ++g_) {
                    f32x4 a = __builtin_amdgcn_mfma_f32_16x16x32_f16(wih[g_][0], b10, biasf[g_], 0, 0, 0);
                    a = __builtin_amdgcn_mfma_f32_16x16x32_f16(wih[g_][1], b11, a, 0, 0, 0);
                    a = __builtin_amdgcn_mfma_f32_16x16x32_f16(whh[g_][0], b20, a, 0, 0, 0);
                    a = __builtin_amdgcn_mfma_f32_16x16x32_f16(whh[g_][1], b21, a, 0, 0, 0);
                    acc[g_] = a;
                }
                if (n < 4) {
                    #pragma unroll
                    for (int r = 0; r < 4; ++r) {
                        const int slot = (16 * quad + 4 * r + n) ^ (quad << 2);
                        f32x4 v = {acc[0][r], acc[1][r], acc[2][r], acc[3][r]};
                        cellC[w][slot] = v;
                    }
                }
                const f32x4 gate = cellC[w][rdslot];
                const float is = sig2_(gate[0]);
                const float fs = sig2_(gate[1]);
                const float gt = tanh2_(gate[2]);
                const float os = sig2_(gate[3]);
                creg = fs * creg + is * gt;
                const float h = os * tanh2_(creg * (2.0f * LOG2E));
                h2T[t & 1][cb * HP + 16 * w + cu] = (_Float16)h;   // h2(t-1)
                if (t == TT) h2f[cb * 68 + 16 * w + cu] = h;       // h2(TT-1) fp32
            }
        }
        __syncthreads();
    }

    // ---- epilogue: logits + softmax on fp32 h2 ----
    if (tid < 16) {
        const int b = tid & 3, o = tid >> 2;
        float acc = b_out[o];
        #pragma unroll
        for (int j = 0; j < HH; ++j)
            acc = fmaf(w_out[o * HH + j], h2f[b * 68 + j], acc);
        lg[b][o] = acc;
    }
    __syncthreads();
    if (tid < NB) {
        const int b = tid;
        const float l0 = lg[b][0], l1 = lg[b][1], l2 = lg[b][2], l3 = lg[b][3];
        const float m  = fmaxf(fmaxf(l0, l1), fmaxf(l2, l3));
        const float e0 = __expf(l0 - m), e1 = __expf(l1 - m);
        const float e2 = __expf(l2 - m), e3 = __expf(l3 - m);
        const float sum = 1.0f / (e0 + e1 + e2 + e3);
        out[(b0 + b) * 4 + 0] = e0 * sum;
        out[(b0 + b) * 4 + 1] = e1 * sum;
        out[(b0 + b) * 4 + 2] = e2 * sum;
        out[(b0 + b) * 4 + 3] = e3 * sum;
    }
}

extern "C" void kernel_launch(void* const* d_in, const int* in_sizes, int n_in,
                              void* d_out, int out_size, void* d_ws, size_t ws_size,
                              hipStream_t stream) {
    const float* x     = (const float*)d_in[0];
    const float* w_ih0 = (const float*)d_in[1];
    const float* w_hh0 = (const float*)d_in[2];
    const float* b_ih0 = (const float*)d_in[3];
    const float* b_hh0 = (const float*)d_in[4];
    const float* w_ih1 = (const float*)d_in[5];
    const float* w_hh1 = (const float*)d_in[6];
    const float* b_ih1 = (const float*)d_in[7];
    const float* b_hh1 = (const float*)d_in[8];
    const float* w_out = (const float*)d_in[9];
    const float* b_out = (const float*)d_in[10];
    float* out = (float*)d_out;

    hipLaunchKernelGGL(lstm_mfma, dim3(NBLK), dim3(512), 0, stream,
                       x, w_ih0, w_hh0, b_ih0, b_hh0,
                       w_ih1, w_hh1, b_ih1, b_hh1,
                       w_out, b_out, out);
}